// Round 3
// baseline (27.080 us; speedup 1.0000x reference)
//
#include <hip/hip_runtime.h>

typedef short short8 __attribute__((ext_vector_type(8)));
typedef float floatx4 __attribute__((ext_vector_type(4)));

#define NEG_INF -9.0e15f

// f32 -> bf16, round-half-up
__device__ __forceinline__ unsigned short f2bf(float x) {
    unsigned int u = __float_as_uint(x);
    return (unsigned short)((u + 0x8000u) >> 16);
}

// ---------------- prep: h fp32 -> bf16 {h_bf, hT_bf, G_bf} in ws ----------------
// grid 256 = (b, jstrip of 32 rows); 256 threads; memory-bound, done ONCE per b.
__global__ __launch_bounds__(256, 4) void gat_prep(
    const float* __restrict__ h,
    const float* __restrict__ a0, const float* __restrict__ a1,
    const float* __restrict__ a2, const float* __restrict__ a3,
    unsigned short* __restrict__ h_bf,    // [b][j][d]
    unsigned short* __restrict__ hT_bf,   // [b][d][j]
    unsigned short* __restrict__ g_bf)    // [b][k][i][d]
{
    __shared__ __align__(16) unsigned short tr[128 * 32];   // [d][j_loc] 8 KB

    const int tid = threadIdx.x;
    const int b   = blockIdx.x >> 2;
    const int j0  = (blockIdx.x & 3) << 5;
    const int jl  = tid >> 3;              // 0..31 local row
    const int row = j0 + jl;
    const int d0  = (tid & 7) << 4;        // 16 d-elems per thread

    const float* hr = h + ((size_t)b << 14) + (size_t)row * 128 + d0;
    float v[16];
    #pragma unroll
    for (int q = 0; q < 4; ++q)
        *reinterpret_cast<float4*>(&v[q * 4]) = *reinterpret_cast<const float4*>(hr + q * 4);

    // h_bf (row-major) + LDS transpose staging
    short8 p0, p1;
    #pragma unroll
    for (int e = 0; e < 8; ++e) { p0[e] = (short)f2bf(v[e]); p1[e] = (short)f2bf(v[8 + e]); }
    unsigned short* hbp = h_bf + ((size_t)b << 14) + (size_t)row * 128 + d0;
    *reinterpret_cast<short8*>(hbp)     = p0;
    *reinterpret_cast<short8*>(hbp + 8) = p1;
    #pragma unroll
    for (int e = 0; e < 8; ++e) {
        tr[(d0 + e) * 32 + jl]     = (unsigned short)p0[e];
        tr[(d0 + 8 + e) * 32 + jl] = (unsigned short)p1[e];
    }

    // G_bf[k] = bf16(h * A_k): single rounding from fp32 inputs
    const float* aptr[4] = {a0, a1, a2, a3};
    #pragma unroll
    for (int k = 0; k < 4; ++k) {
        float af[16];
        #pragma unroll
        for (int q = 0; q < 4; ++q)
            *reinterpret_cast<float4*>(&af[q * 4]) = *reinterpret_cast<const float4*>(aptr[k] + d0 + q * 4);
        short8 g0, g1;
        #pragma unroll
        for (int e = 0; e < 8; ++e) {
            g0[e] = (short)f2bf(v[e] * af[e]);
            g1[e] = (short)f2bf(v[8 + e] * af[8 + e]);
        }
        unsigned short* gp = g_bf + ((((size_t)b << 2) + k) << 14) + (size_t)row * 128 + d0;
        *reinterpret_cast<short8*>(gp)     = g0;
        *reinterpret_cast<short8*>(gp + 8) = g1;
    }

    __syncthreads();

    // transposed write-out: thread t -> row d = t>>1, j-half = (t&1)*16
    const int d  = tid >> 1;
    const int jh = (tid & 1) << 4;
    short8 t0 = *reinterpret_cast<const short8*>(&tr[d * 32 + jh]);
    short8 t1 = *reinterpret_cast<const short8*>(&tr[d * 32 + jh + 8]);
    unsigned short* htp = hT_bf + ((size_t)b << 14) + (size_t)d * 128 + j0 + jh;
    *reinterpret_cast<short8*>(htp)     = t0;
    *reinterpret_cast<short8*>(htp + 8) = t1;
}

// ---------------- main: MFMA scores + softmax + MFMA aggregate ----------------
// grid 512 = (b, i-strip of 16); 256 threads; LDS only 4.5 KB.
__global__ __launch_bounds__(256, 2) void gat_main(
    const unsigned short* __restrict__ h_bf,
    const unsigned short* __restrict__ hT_bf,
    const unsigned short* __restrict__ g_bf,
    const int* __restrict__ adj,
    float* __restrict__ out)
{
    __shared__ __align__(16) unsigned short al_lds[16 * 128]; // swizzled alpha, 4 KB
    __shared__ float red_lds[16 * 8];                         // per-wave (m,s) partials

    const int tid  = threadIdx.x;
    const int b    = blockIdx.x >> 3;
    const int i0   = (blockIdx.x & 7) << 4;
    const int w    = tid >> 6;
    const int lane = tid & 63;
    const int c    = lane & 15;
    const int g    = lane >> 4;

    const unsigned short* hb  = h_bf  + ((size_t)b << 14);
    const unsigned short* htb = hT_bf + ((size_t)b << 14);

    // ---- issue all global loads up front (L2-resident after prep) ----
    const int jA = (w << 5) + c;
    const int jB = jA + 16;
    short8 bA[4], bB[4];
    #pragma unroll
    for (int s = 0; s < 4; ++s) {
        bA[s] = *reinterpret_cast<const short8*>(hb + jA * 128 + (s << 5) + (g << 3));
        bB[s] = *reinterpret_cast<const short8*>(hb + jB * 128 + (s << 5) + (g << 3));
    }
    short8 gfr[4][4];
    const unsigned short* gbase = g_bf + (((size_t)b << 2) << 14) + (size_t)(i0 + c) * 128 + (g << 3);
    #pragma unroll
    for (int k = 0; k < 4; ++k)
        #pragma unroll
        for (int s = 0; s < 4; ++s)
            gfr[k][s] = *reinterpret_cast<const short8*>(gbase + ((size_t)k << 14) + (s << 5));
    int adjv[2][4];
    #pragma unroll
    for (int jt = 0; jt < 2; ++jt)
        #pragma unroll
        for (int r = 0; r < 4; ++r)
            adjv[jt][r] = adj[((size_t)b << 14) + (size_t)(i0 + (g << 2) + r) * 128
                              + ((w << 5) + (jt << 4) + c)];

    // ---- phase 1: e_k tiles (wave w owns j in [32w, 32w+32)) ----
    floatx4 acc[2][4];
    #pragma unroll
    for (int jt = 0; jt < 2; ++jt)
        #pragma unroll
        for (int k = 0; k < 4; ++k) acc[jt][k] = (floatx4){0.f, 0.f, 0.f, 0.f};
    #pragma unroll
    for (int s = 0; s < 4; ++s)
        #pragma unroll
        for (int k = 0; k < 4; ++k) {
            acc[0][k] = __builtin_amdgcn_mfma_f32_16x16x32_bf16(gfr[k][s], bA[s], acc[0][k], 0, 0, 0);
            acc[1][k] = __builtin_amdgcn_mfma_f32_16x16x32_bf16(gfr[k][s], bB[s], acc[1][k], 0, 0, 0);
        }

    // ---- select + leaky-relu + mask ----
    float sc[2][4], p[2][4], pm[4];
    #pragma unroll
    for (int jt = 0; jt < 2; ++jt)
        #pragma unroll
        for (int r = 0; r < 4; ++r) {
            int cd = adjv[jt][r];
            float vv = (cd == 1) ? acc[jt][0][r] :
                       (cd == 2) ? acc[jt][1][r] :
                       (cd == 3) ? acc[jt][2][r] : acc[jt][3][r];
            vv = (vv > 0.f) ? vv : 0.2f * vv;
            sc[jt][r] = (cd == 0) ? NEG_INF : vv;
        }

    // ---- per-wave partial softmax over 32 cols ----
    #pragma unroll
    for (int r = 0; r < 4; ++r) {
        float m = fmaxf(sc[0][r], sc[1][r]);
        #pragma unroll
        for (int mk = 1; mk < 16; mk <<= 1) m = fmaxf(m, __shfl_xor(m, mk));
        float e0 = __expf(sc[0][r] - m);
        float e1 = __expf(sc[1][r] - m);
        float ss = e0 + e1;
        #pragma unroll
        for (int mk = 1; mk < 16; mk <<= 1) ss += __shfl_xor(ss, mk);
        pm[r] = m; p[0][r] = e0; p[1][r] = e1;
        if (c == 0) {
            int row = (g << 2) + r;
            red_lds[row * 8 + w * 2]     = m;
            red_lds[row * 8 + w * 2 + 1] = ss;
        }
    }
    __syncthreads();

    // ---- combine wave partials, write bf16 alpha (swizzled) ----
    #pragma unroll
    for (int r = 0; r < 4; ++r) {
        int row = (g << 2) + r;
        float4 q0 = *reinterpret_cast<const float4*>(&red_lds[row * 8]);
        float4 q1 = *reinterpret_cast<const float4*>(&red_lds[row * 8 + 4]);
        float M = fmaxf(fmaxf(q0.x, q0.z), fmaxf(q1.x, q1.z));
        float S = q0.y * __expf(q0.x - M) + q0.w * __expf(q0.z - M)
                + q1.y * __expf(q1.x - M) + q1.w * __expf(q1.z - M);
        float scale = __expf(pm[r] - M) / S;
        #pragma unroll
        for (int jt = 0; jt < 2; ++jt) {
            int col = (w << 5) + (jt << 4) + c;
            al_lds[row * 128 + (((col >> 3) ^ (row & 7)) << 3) + (col & 7)]
                = f2bf(p[jt][r] * scale);
        }
    }
    __syncthreads();

    // ---- phase 3: out = alpha @ h (wave w owns d in [32w, 32w+32)) ----
    const int dA = (w << 5) + c;
    const int dB = dA + 16;
    floatx4 oa0 = (floatx4){0.f, 0.f, 0.f, 0.f};
    floatx4 oa1 = (floatx4){0.f, 0.f, 0.f, 0.f};
    #pragma unroll
    for (int s = 0; s < 4; ++s) {
        int ch = (s << 2) + g;
        short8 afr = *reinterpret_cast<const short8*>(&al_lds[c * 128 + ((ch ^ (c & 7)) << 3)]);
        short8 tA  = *reinterpret_cast<const short8*>(htb + dA * 128 + (s << 5) + (g << 3));
        short8 tB  = *reinterpret_cast<const short8*>(htb + dB * 128 + (s << 5) + (g << 3));
        oa0 = __builtin_amdgcn_mfma_f32_16x16x32_bf16(afr, tA, oa0, 0, 0, 0);
        oa1 = __builtin_amdgcn_mfma_f32_16x16x32_bf16(afr, tB, oa1, 0, 0, 0);
    }
    float* ob = out + ((size_t)b << 14);
    #pragma unroll
    for (int r = 0; r < 4; ++r) {
        int rw = (i0 + (g << 2) + r) * 128;
        ob[rw + (w << 5) + c]      = oa0[r];
        ob[rw + (w << 5) + 16 + c] = oa1[r];
    }
}

extern "C" void kernel_launch(void* const* d_in, const int* in_sizes, int n_in,
                              void* d_out, int out_size, void* d_ws, size_t ws_size,
                              hipStream_t stream) {
    const float* h   = (const float*)d_in[0];
    const int*   adj = (const int*)d_in[1];
    const float* a0  = (const float*)d_in[2];
    const float* a1  = (const float*)d_in[3];
    const float* a2  = (const float*)d_in[4];
    const float* a3  = (const float*)d_in[5];
    float* out = (float*)d_out;

    unsigned short* h_bf  = (unsigned short*)d_ws;           // 2 MB
    unsigned short* hT_bf = h_bf  + (size_t)64 * 128 * 128;  // 2 MB
    unsigned short* g_bf  = hT_bf + (size_t)64 * 128 * 128;  // 8 MB

    gat_prep<<<dim3(256), dim3(256), 0, stream>>>(h, a0, a1, a2, a3, h_bf, hT_bf, g_bf);
    gat_main<<<dim3(512), dim3(256), 0, stream>>>(h_bf, hT_bf, g_bf, adj, out);
}

// Round 4
// 16.534 us; speedup vs baseline: 1.6378x; 1.6378x over previous
//
#include <hip/hip_runtime.h>

typedef short short8 __attribute__((ext_vector_type(8)));
typedef float floatx4 __attribute__((ext_vector_type(4)));

#define NEG_INF -9.0e15f

// f32 -> bf16, round-half-up (2 VALU)
__device__ __forceinline__ unsigned short f2bf(float x) {
    unsigned int u = __float_as_uint(x);
    return (unsigned short)((u + 0x8000u) >> 16);
}

// element index of (row,col) in a 128-col bf16 tile with 16B-chunk XOR swizzle
__device__ __forceinline__ int swzi(int row, int col) {
    return row * 128 + ((((col >> 3) ^ (row & 7)) << 3) | (col & 7));
}

__global__ __launch_bounds__(512, 4) void gat_fused(
    const float* __restrict__ h,
    const int*   __restrict__ adj,
    const float* __restrict__ a0, const float* __restrict__ a1,
    const float* __restrict__ a2, const float* __restrict__ a3,
    float* __restrict__ out)
{
    // 32K + 32K + 16K = 81920 B exactly -> 2 blocks/CU (160 KB/CU)
    __shared__ __align__(16) unsigned short h_lds [128 * 128]; // [j][d] swizzled
    __shared__ __align__(16) unsigned short hT_lds[128 * 128]; // [d][j] swizzled
    __shared__ __align__(16) unsigned char  u_lds [16384];     // G | red+alpha

    unsigned short* Gl  = reinterpret_cast<unsigned short*>(u_lds);        // [4][16][128] bf16
    float2*         red = reinterpret_cast<float2*>(u_lds);                // [16][8] (m,s)
    unsigned short* al  = reinterpret_cast<unsigned short*>(u_lds + 1024); // [16][128] bf16

    const int tid = threadIdx.x;
    const int B_  = blockIdx.x;
    // XCD-colocate the 8 strips of each b (HW xcd = blockIdx % 8 heuristic)
    const int b   = ((B_ & 7) << 3) + (B_ >> 6);
    const int i0  = ((B_ >> 3) & 7) << 4;

    const int w    = tid >> 6;   // wave 0..7
    const int lane = tid & 63;
    const int c    = lane & 15;
    const int g    = lane >> 4;

    const float* __restrict__ hb = h + ((size_t)b << 14);

    // ---- G source loads (fp32; single-rounding product later) ----
    const int gk = tid >> 7;          // k 0..3 (wave-uniform)
    const int gr = (tid >> 3) & 15;   // i_loc
    const int gd = (tid & 7) << 4;    // d0
    const float* __restrict__ ap = (gk == 0) ? a0 : (gk == 1) ? a1 : (gk == 2) ? a2 : a3;
    float ghv[16], gav[16];
    #pragma unroll
    for (int q = 0; q < 4; ++q) {
        *reinterpret_cast<float4*>(&ghv[q * 4]) =
            *reinterpret_cast<const float4*>(&hb[(i0 + gr) * 128 + gd + q * 4]);
        *reinterpret_cast<float4*>(&gav[q * 4]) =
            *reinterpret_cast<const float4*>(&ap[gd + q * 4]);
    }

    // ---- adj for this thread's e-tile cells ----
    int adjv[4];
    #pragma unroll
    for (int rr = 0; rr < 4; ++rr)
        adjv[rr] = adj[((size_t)b << 14) + (size_t)(i0 + (g << 2) + rr) * 128 + (w << 4) + c];

    // ---- stage h_lds: bf16 row-major, chunk-swizzled (proven r1 layout) ----
    {
        const float4* __restrict__ src = reinterpret_cast<const float4*>(hb);
        #pragma unroll
        for (int it = 0; it < 8; ++it) {
            int id  = (it << 9) + tid;   // 4096 float4 chunks
            int row = id >> 5, c4 = id & 31;
            float4 v = src[id];
            short4 pk;
            pk.x = (short)f2bf(v.x); pk.y = (short)f2bf(v.y);
            pk.z = (short)f2bf(v.z); pk.w = (short)f2bf(v.w);
            *reinterpret_cast<short4*>(
                &h_lds[row * 128 + (((c4 >> 1) ^ (row & 7)) << 3) + ((c4 & 1) << 2)]) = pk;
        }
    }
    __syncthreads(); // bar0: h_lds ready

    // ---- build hT_lds (LDS transpose of h_lds) + build G into union ----
    {
        const int tj = tid >> 2;   // j row 0..127
        const int ts = tid & 3;    // d-quarter
        #pragma unroll
        for (int q = 0; q < 4; ++q) {
            int chunk = (ts << 2) + q;
            short8 v8 = *reinterpret_cast<const short8*>(
                &h_lds[tj * 128 + ((chunk ^ (tj & 7)) << 3)]);
            #pragma unroll
            for (int e = 0; e < 8; ++e) {
                int d = (chunk << 3) + e;
                hT_lds[d * 128 + (((tj >> 3) ^ (d & 7)) << 3) + (tj & 7)] =
                    (unsigned short)v8[e];
            }
        }
        short8 g0, g1;
        #pragma unroll
        for (int e = 0; e < 8; ++e) {
            g0[e] = (short)f2bf(ghv[e] * gav[e]);
            g1[e] = (short)f2bf(ghv[8 + e] * gav[8 + e]);
        }
        int cb   = gd >> 3;                  // even chunk id
        int base = (gk << 11) + gr * 128;
        *reinterpret_cast<short8*>(&Gl[base + ((cb ^ (gr & 7)) << 3)])       = g0;
        *reinterpret_cast<short8*>(&Gl[base + (((cb + 1) ^ (gr & 7)) << 3)]) = g1;
    }
    __syncthreads(); // bar1: hT, G ready

    // ---- phase 1: e_k tiles; wave w owns j-tile w ----
    floatx4 acc[4];
    #pragma unroll
    for (int k = 0; k < 4; ++k) acc[k] = (floatx4){0.f, 0.f, 0.f, 0.f};
    const int jrow = (w << 4) + c;
    #pragma unroll
    for (int s = 0; s < 4; ++s) {
        int ch = (s << 2) + g;
        short8 bfr = *reinterpret_cast<const short8*>(
            &h_lds[jrow * 128 + ((ch ^ (jrow & 7)) << 3)]);
        #pragma unroll
        for (int k = 0; k < 4; ++k) {
            short8 gfr = *reinterpret_cast<const short8*>(
                &Gl[(k << 11) + c * 128 + ((ch ^ (c & 7)) << 3)]);
            acc[k] = __builtin_amdgcn_mfma_f32_16x16x32_bf16(gfr, bfr, acc[k], 0, 0, 0);
        }
    }

    // ---- select + leaky-relu + mask; per-wave partial softmax (16 cols) ----
    float p[4], pm[4], psv[4];
    #pragma unroll
    for (int rr = 0; rr < 4; ++rr) {
        int cd = adjv[rr];
        float v = (cd == 1) ? acc[0][rr] : (cd == 2) ? acc[1][rr] :
                  (cd == 3) ? acc[2][rr] : acc[3][rr];
        v = (v > 0.f) ? v : 0.2f * v;
        float scv = (cd == 0) ? NEG_INF : v;
        float m = scv;
        #pragma unroll
        for (int mk = 1; mk < 16; mk <<= 1) m = fmaxf(m, __shfl_xor(m, mk));
        float ev = __expf(scv - m);
        float ss = ev;
        #pragma unroll
        for (int mk = 1; mk < 16; mk <<= 1) ss += __shfl_xor(ss, mk);
        p[rr] = ev; pm[rr] = m; psv[rr] = ss;
    }
    __syncthreads(); // bar2: all G reads complete; union reusable
    if (c == 0) {
        #pragma unroll
        for (int rr = 0; rr < 4; ++rr)
            red[((g << 2) + rr) * 8 + w] = make_float2(pm[rr], psv[rr]);
    }
    __syncthreads(); // bar3: partials ready

    // ---- combine partials; write bf16 alpha (swizzled) ----
    #pragma unroll
    for (int rr = 0; rr < 4; ++rr) {
        int row = (g << 2) + rr;
        const float4* rp = reinterpret_cast<const float4*>(&red[row * 8]);
        float4 q0 = rp[0], q1 = rp[1], q2 = rp[2], q3 = rp[3];
        float M = fmaxf(fmaxf(fmaxf(q0.x, q0.z), fmaxf(q1.x, q1.z)),
                        fmaxf(fmaxf(q2.x, q2.z), fmaxf(q3.x, q3.z)));
        float S = q0.y * __expf(q0.x - M) + q0.w * __expf(q0.z - M)
                + q1.y * __expf(q1.x - M) + q1.w * __expf(q1.z - M)
                + q2.y * __expf(q2.x - M) + q2.w * __expf(q2.z - M)
                + q3.y * __expf(q3.x - M) + q3.w * __expf(q3.z - M);
        float scale = __expf(pm[rr] - M) / S;
        al[swzi(row, jrow)] = f2bf(p[rr] * scale);
    }
    __syncthreads(); // bar4: alpha ready

    // ---- phase 3: out = alpha @ h; wave w owns d-tile w ----
    floatx4 oa = (floatx4){0.f, 0.f, 0.f, 0.f};
    const int drow = (w << 4) + c;
    #pragma unroll
    for (int s = 0; s < 4; ++s) {
        int ch = (s << 2) + g;
        short8 afr = *reinterpret_cast<const short8*>(&al[c * 128 + ((ch ^ (c & 7)) << 3)]);
        short8 bfr = *reinterpret_cast<const short8*>(
            &hT_lds[drow * 128 + ((ch ^ (drow & 7)) << 3)]);
        oa = __builtin_amdgcn_mfma_f32_16x16x32_bf16(afr, bfr, oa, 0, 0, 0);
    }
    float* __restrict__ ob = out + ((size_t)b << 14);
    #pragma unroll
    for (int rr = 0; rr < 4; ++rr)
        ob[(size_t)(i0 + (g << 2) + rr) * 128 + drow] = oa[rr];
}

extern "C" void kernel_launch(void* const* d_in, const int* in_sizes, int n_in,
                              void* d_out, int out_size, void* d_ws, size_t ws_size,
                              hipStream_t stream) {
    const float* h   = (const float*)d_in[0];
    const int*   adj = (const int*)d_in[1];
    const float* a0  = (const float*)d_in[2];
    const float* a1  = (const float*)d_in[3];
    const float* a2  = (const float*)d_in[4];
    const float* a3  = (const float*)d_in[5];
    float* out = (float*)d_out;
    gat_fused<<<dim3(512), dim3(512), 0, stream>>>(h, adj, a0, a1, a2, a3, out);
}

// Round 5
// 13.789 us; speedup vs baseline: 1.9639x; 1.1991x over previous
//
#include <hip/hip_runtime.h>

typedef short short8 __attribute__((ext_vector_type(8)));
typedef float floatx4 __attribute__((ext_vector_type(4)));

#define NEG_INF -9.0e15f

// f32 -> bf16, round-half-up (2 VALU)
__device__ __forceinline__ unsigned short f2bf(float x) {
    unsigned int u = __float_as_uint(x);
    return (unsigned short)((u + 0x8000u) >> 16);
}

__global__ __launch_bounds__(512, 4) void gat_fused(
    const float* __restrict__ h,
    const int*   __restrict__ adj,
    const float* __restrict__ a0, const float* __restrict__ a1,
    const float* __restrict__ a2, const float* __restrict__ a3,
    float* __restrict__ out)
{
    // 32 KB h-tile (becomes hT in place) + 16 KB union = 48 KB -> >=2 blocks/CU
    __shared__ __align__(16) unsigned short h_lds[128 * 128]; // [j][d] swizzled, later [d][j]
    __shared__ __align__(16) unsigned char  u_lds[16384];     // G | red+alpha

    unsigned short* Gl  = reinterpret_cast<unsigned short*>(u_lds);        // [4][16][128] bf16
    float*          red = reinterpret_cast<float*>(u_lds);                 // [16][8] partial sums
    unsigned short* al  = reinterpret_cast<unsigned short*>(u_lds + 512);  // [16][128] bf16

    const int tid = threadIdx.x;
    const int B_  = blockIdx.x;
    // XCD-colocate the 8 i-strips of each b
    const int b   = ((B_ & 7) << 3) + (B_ >> 6);
    const int i0  = ((B_ >> 3) & 7) << 4;

    const int w    = tid >> 6;   // wave 0..7
    const int lane = tid & 63;
    const int c    = lane & 15;
    const int g    = lane >> 4;
    const int jrow = (w << 4) + c;

    const float* __restrict__ hb = h + ((size_t)b << 14);

    // ---- adj loads (issued early; 4 regs live) ----
    int adjv[4];
    #pragma unroll
    for (int rr = 0; rr < 4; ++rr)
        adjv[rr] = adj[((size_t)b << 14) + (size_t)(i0 + (g << 2) + rr) * 128 + jrow];

    // ---- G build first: Gl[k][i_loc][d] = bf16(h*a_k); source regs die here ----
    {
        const int gk = tid >> 7;          // k (wave-uniform)
        const int gr = (tid >> 3) & 15;   // i_loc
        const int gd = (tid & 7) << 4;    // d0
        const float* __restrict__ ap = (gk == 0) ? a0 : (gk == 1) ? a1 : (gk == 2) ? a2 : a3;
        float hv[16], av[16];
        #pragma unroll
        for (int q = 0; q < 4; ++q) {
            *reinterpret_cast<float4*>(&hv[q * 4]) =
                *reinterpret_cast<const float4*>(&hb[(i0 + gr) * 128 + gd + q * 4]);
            *reinterpret_cast<float4*>(&av[q * 4]) =
                *reinterpret_cast<const float4*>(&ap[gd + q * 4]);
        }
        short8 g0, g1;
        #pragma unroll
        for (int e = 0; e < 8; ++e) {
            g0[e] = (short)f2bf(hv[e]     * av[e]);
            g1[e] = (short)f2bf(hv[8 + e] * av[8 + e]);
        }
        const int cb   = gd >> 3;
        const int base = (gk << 11) + gr * 128;
        *reinterpret_cast<short8*>(&Gl[base + ((cb ^ (gr & 7)) << 3)])       = g0;
        *reinterpret_cast<short8*>(&Gl[base + (((cb + 1) ^ (gr & 7)) << 3)]) = g1;
    }

    // ---- stage h_lds: bf16, 16B-chunk XOR swizzle (proven layout) ----
    {
        const float4* __restrict__ src = reinterpret_cast<const float4*>(hb);
        #pragma unroll
        for (int it = 0; it < 8; ++it) {
            int id  = (it << 9) + tid;
            int row = id >> 5, c4 = id & 31;
            float4 v = src[id];
            short4 pk;
            pk.x = (short)f2bf(v.x); pk.y = (short)f2bf(v.y);
            pk.z = (short)f2bf(v.z); pk.w = (short)f2bf(v.w);
            *reinterpret_cast<short4*>(
                &h_lds[row * 128 + (((c4 >> 1) ^ (row & 7)) << 3) + ((c4 & 1) << 2)]) = pk;
        }
    }
    __syncthreads(); // bar0: h_lds + Gl ready

    // ---- phase 1: e_k tiles (wave w -> j-tile w) ----
    floatx4 acc[4];
    #pragma unroll
    for (int k = 0; k < 4; ++k) acc[k] = (floatx4){0.f, 0.f, 0.f, 0.f};
    #pragma unroll
    for (int s = 0; s < 4; ++s) {
        int ch = (s << 2) + g;
        short8 bfr = *reinterpret_cast<const short8*>(
            &h_lds[jrow * 128 + ((ch ^ (jrow & 7)) << 3)]);
        #pragma unroll
        for (int k = 0; k < 4; ++k) {
            short8 gfr = *reinterpret_cast<const short8*>(
                &Gl[(k << 11) + c * 128 + ((ch ^ (c & 7)) << 3)]);
            acc[k] = __builtin_amdgcn_mfma_f32_16x16x32_bf16(gfr, bfr, acc[k], 0, 0, 0);
        }
    }

    // ---- transpose gather (reads h_lds before bar1; packed immediately) ----
    const int jp = lane;           // j-pair 0..63 (wave covers all rows)
    const int dq = w;              // d-chunk-of-16
    const int r0 = 2 * jp, r1 = 2 * jp + 1;
    short8 t00 = *reinterpret_cast<const short8*>(&h_lds[r0 * 128 + (((2 * dq)     ^ (r0 & 7)) << 3)]);
    short8 t01 = *reinterpret_cast<const short8*>(&h_lds[r0 * 128 + (((2 * dq + 1) ^ (r0 & 7)) << 3)]);
    short8 t10 = *reinterpret_cast<const short8*>(&h_lds[r1 * 128 + (((2 * dq)     ^ (r1 & 7)) << 3)]);
    short8 t11 = *reinterpret_cast<const short8*>(&h_lds[r1 * 128 + (((2 * dq + 1) ^ (r1 & 7)) << 3)]);
    unsigned int tw[16];
    #pragma unroll
    for (int e = 0; e < 8; ++e) {
        tw[e]     = (unsigned int)(unsigned short)t00[e] | ((unsigned int)(unsigned short)t10[e] << 16);
        tw[8 + e] = (unsigned int)(unsigned short)t01[e] | ((unsigned int)(unsigned short)t11[e] << 16);
    }

    // ---- select + leaky-relu + mask + exp; no-max softmax (scores bounded) ----
    float p[4], psv[4];
    #pragma unroll
    for (int rr = 0; rr < 4; ++rr) {
        int cd = adjv[rr];
        float v = (cd == 1) ? acc[0][rr] : (cd == 2) ? acc[1][rr] :
                  (cd == 3) ? acc[2][rr] : acc[3][rr];
        v = (v > 0.f) ? v : 0.2f * v;
        float scv = (cd == 0) ? NEG_INF : v;
        float ev = __expf(scv);                 // masked -> 0
        float ss = ev;
        #pragma unroll
        for (int mk = 1; mk < 16; mk <<= 1) ss += __shfl_xor(ss, mk);
        p[rr] = ev; psv[rr] = ss;
    }
    __syncthreads(); // bar1: ALL h_lds + Gl reads complete

    // ---- in-place transpose write: h_lds becomes hT[d][j] (same swizzle) ----
    #pragma unroll
    for (int e = 0; e < 16; ++e) {
        int d    = (dq << 4) + e;
        int elem = d * 128 + (((jp >> 2) ^ (d & 7)) << 3) + ((jp & 3) << 1);
        *reinterpret_cast<unsigned int*>(&h_lds[elem]) = tw[e];
    }
    if (c == 0) {
        #pragma unroll
        for (int rr = 0; rr < 4; ++rr)
            red[((g << 2) + rr) * 8 + w] = psv[rr];
    }
    __syncthreads(); // bar2: hT + red ready

    // ---- normalize, write bf16 alpha (swizzled) ----
    #pragma unroll
    for (int rr = 0; rr < 4; ++rr) {
        int row = (g << 2) + rr;
        float4 s0 = *reinterpret_cast<const float4*>(&red[row * 8]);
        float4 s1 = *reinterpret_cast<const float4*>(&red[row * 8 + 4]);
        float S = ((s0.x + s0.y) + (s0.z + s0.w)) + ((s1.x + s1.y) + (s1.z + s1.w));
        float inv = 1.0f / S;
        al[row * 128 + (((jrow >> 3) ^ (row & 7)) << 3) + (jrow & 7)] = f2bf(p[rr] * inv);
    }
    __syncthreads(); // bar3: alpha ready

    // ---- phase 3: out = alpha @ h via in-place hT; wave w -> d-tile w ----
    floatx4 oa = (floatx4){0.f, 0.f, 0.f, 0.f};
    const int drow = jrow;
    #pragma unroll
    for (int s = 0; s < 4; ++s) {
        int ch = (s << 2) + g;
        short8 afr = *reinterpret_cast<const short8*>(&al[c * 128 + ((ch ^ (c & 7)) << 3)]);
        short8 bfr = *reinterpret_cast<const short8*>(
            &h_lds[drow * 128 + ((ch ^ (drow & 7)) << 3)]);
        oa = __builtin_amdgcn_mfma_f32_16x16x32_bf16(afr, bfr, oa, 0, 0, 0);
    }
    float* __restrict__ ob = out + ((size_t)b << 14);
    #pragma unroll
    for (int rr = 0; rr < 4; ++rr)
        ob[(size_t)(i0 + (g << 2) + rr) * 128 + drow] = oa[rr];
}

extern "C" void kernel_launch(void* const* d_in, const int* in_sizes, int n_in,
                              void* d_out, int out_size, void* d_ws, size_t ws_size,
                              hipStream_t stream) {
    const float* h   = (const float*)d_in[0];
    const int*   adj = (const int*)d_in[1];
    const float* a0  = (const float*)d_in[2];
    const float* a1  = (const float*)d_in[3];
    const float* a2  = (const float*)d_in[4];
    const float* a3  = (const float*)d_in[5];
    float* out = (float*)d_out;
    (void)d_ws; (void)ws_size; (void)in_sizes; (void)n_in; (void)out_size;
    gat_fused<<<dim3(512), dim3(512), 0, stream>>>(h, adj, a0, a1, a2, a3, out);
}

// Round 6
// 13.572 us; speedup vs baseline: 1.9953x; 1.0160x over previous
//
#include <hip/hip_runtime.h>

typedef short short8 __attribute__((ext_vector_type(8)));
typedef float floatx4 __attribute__((ext_vector_type(4)));

#define NEG_INF -9.0e15f

// f32 -> bf16, round-half-up (2 VALU)
__device__ __forceinline__ unsigned short f2bf(float x) {
    unsigned int u = __float_as_uint(x);
    return (unsigned short)((u + 0x8000u) >> 16);
}

__global__ __launch_bounds__(512, 4) void gat_fused(
    const float* __restrict__ h,
    const int*   __restrict__ adj,
    const float* __restrict__ a0, const float* __restrict__ a1,
    const float* __restrict__ a2, const float* __restrict__ a3,
    float* __restrict__ out)
{
    // 32 KB h-tile (becomes hT in place) + 16 KB union = 48 KB -> 2 blocks/CU
    __shared__ __align__(16) unsigned short h_lds[128 * 128]; // [j][d] swizzled, later [d][j]
    __shared__ __align__(16) unsigned char  u_lds[16384];     // G | red+alpha

    unsigned short* Gl  = reinterpret_cast<unsigned short*>(u_lds);        // [4][16][128] bf16
    float*          red = reinterpret_cast<float*>(u_lds);                 // [16][8] partial sums
    unsigned short* al  = reinterpret_cast<unsigned short*>(u_lds + 512);  // [16][128] bf16 (unnormalized)

    const int tid = threadIdx.x;
    const int B_  = blockIdx.x;
    // XCD-colocate the 8 i-strips of each b
    const int b   = ((B_ & 7) << 3) + (B_ >> 6);
    const int i0  = ((B_ >> 3) & 7) << 4;

    const int w    = tid >> 6;   // wave 0..7
    const int lane = tid & 63;
    const int c    = lane & 15;
    const int g    = lane >> 4;
    const int jrow = (w << 4) + c;

    const float* __restrict__ hb = h + ((size_t)b << 14);

    // ---- adj loads (issued early; 4 regs live) ----
    int adjv[4];
    #pragma unroll
    for (int rr = 0; rr < 4; ++rr)
        adjv[rr] = adj[((size_t)b << 14) + (size_t)(i0 + (g << 2) + rr) * 128 + jrow];

    // ---- G build first: Gl[k][i_loc][d] = bf16(h*a_k); source regs die here ----
    {
        const int gk = tid >> 7;          // k (wave-uniform)
        const int gr = (tid >> 3) & 15;   // i_loc
        const int gd = (tid & 7) << 4;    // d0
        const float* __restrict__ ap = (gk == 0) ? a0 : (gk == 1) ? a1 : (gk == 2) ? a2 : a3;
        float hv[16], av[16];
        #pragma unroll
        for (int q = 0; q < 4; ++q) {
            *reinterpret_cast<float4*>(&hv[q * 4]) =
                *reinterpret_cast<const float4*>(&hb[(i0 + gr) * 128 + gd + q * 4]);
            *reinterpret_cast<float4*>(&av[q * 4]) =
                *reinterpret_cast<const float4*>(&ap[gd + q * 4]);
        }
        short8 g0, g1;
        #pragma unroll
        for (int e = 0; e < 8; ++e) {
            g0[e] = (short)f2bf(hv[e]     * av[e]);
            g1[e] = (short)f2bf(hv[8 + e] * av[8 + e]);
        }
        const int cb   = gd >> 3;
        const int base = (gk << 11) + gr * 128;
        *reinterpret_cast<short8*>(&Gl[base + ((cb ^ (gr & 7)) << 3)])       = g0;
        *reinterpret_cast<short8*>(&Gl[base + (((cb + 1) ^ (gr & 7)) << 3)]) = g1;
    }

    // ---- stage h_lds: bf16, 16B-chunk XOR swizzle (proven layout) ----
    {
        const float4* __restrict__ src = reinterpret_cast<const float4*>(hb);
        #pragma unroll
        for (int it = 0; it < 8; ++it) {
            int id  = (it << 9) + tid;
            int row = id >> 5, c4 = id & 31;
            float4 v = src[id];
            short4 pk;
            pk.x = (short)f2bf(v.x); pk.y = (short)f2bf(v.y);
            pk.z = (short)f2bf(v.z); pk.w = (short)f2bf(v.w);
            *reinterpret_cast<short4*>(
                &h_lds[row * 128 + (((c4 >> 1) ^ (row & 7)) << 3) + ((c4 & 1) << 2)]) = pk;
        }
    }
    __syncthreads(); // bar0: h_lds + Gl ready

    // ---- phase 1: e_k tiles (wave w -> j-tile w) ----
    floatx4 acc[4];
    #pragma unroll
    for (int k = 0; k < 4; ++k) acc[k] = (floatx4){0.f, 0.f, 0.f, 0.f};
    #pragma unroll
    for (int s = 0; s < 4; ++s) {
        int ch = (s << 2) + g;
        short8 bfr = *reinterpret_cast<const short8*>(
            &h_lds[jrow * 128 + ((ch ^ (jrow & 7)) << 3)]);
        #pragma unroll
        for (int k = 0; k < 4; ++k) {
            short8 gfr = *reinterpret_cast<const short8*>(
                &Gl[(k << 11) + c * 128 + ((ch ^ (c & 7)) << 3)]);
            acc[k] = __builtin_amdgcn_mfma_f32_16x16x32_bf16(gfr, bfr, acc[k], 0, 0, 0);
        }
    }

    // ---- transpose gather (reads h_lds before bar1; packed immediately) ----
    const int jp = lane;           // j-pair 0..63 (wave covers all rows)
    const int dq = w;              // d-chunk-of-16
    const int r0 = 2 * jp, r1 = 2 * jp + 1;
    short8 t00 = *reinterpret_cast<const short8*>(&h_lds[r0 * 128 + (((2 * dq)     ^ (r0 & 7)) << 3)]);
    short8 t01 = *reinterpret_cast<const short8*>(&h_lds[r0 * 128 + (((2 * dq + 1) ^ (r0 & 7)) << 3)]);
    short8 t10 = *reinterpret_cast<const short8*>(&h_lds[r1 * 128 + (((2 * dq)     ^ (r1 & 7)) << 3)]);
    short8 t11 = *reinterpret_cast<const short8*>(&h_lds[r1 * 128 + (((2 * dq + 1) ^ (r1 & 7)) << 3)]);
    unsigned int tw[16];
    #pragma unroll
    for (int e = 0; e < 8; ++e) {
        tw[e]     = (unsigned int)(unsigned short)t00[e] | ((unsigned int)(unsigned short)t10[e] << 16);
        tw[8 + e] = (unsigned int)(unsigned short)t01[e] | ((unsigned int)(unsigned short)t11[e] << 16);
    }

    // ---- select + leaky-relu + mask + exp; no-max softmax (scores bounded) ----
    float p[4], psv[4];
    #pragma unroll
    for (int rr = 0; rr < 4; ++rr) {
        int cd = adjv[rr];
        float v = (cd == 1) ? acc[0][rr] : (cd == 2) ? acc[1][rr] :
                  (cd == 3) ? acc[2][rr] : acc[3][rr];
        v = (v > 0.f) ? v : 0.2f * v;
        float scv = (cd == 0) ? NEG_INF : v;
        float ev = __expf(scv);                 // masked -> 0
        float ss = ev;
        #pragma unroll
        for (int mk = 1; mk < 16; mk <<= 1) ss += __shfl_xor(ss, mk);
        p[rr] = ev; psv[rr] = ss;
    }
    __syncthreads(); // bar1: ALL h_lds + Gl reads complete

    // ---- in-place transpose write (h_lds -> hT), UNNORMALIZED alpha, red partials ----
    #pragma unroll
    for (int e = 0; e < 16; ++e) {
        int d    = (dq << 4) + e;
        int elem = d * 128 + (((jp >> 2) ^ (d & 7)) << 3) + ((jp & 3) << 1);
        *reinterpret_cast<unsigned int*>(&h_lds[elem]) = tw[e];
    }
    #pragma unroll
    for (int rr = 0; rr < 4; ++rr) {
        int row = (g << 2) + rr;
        al[row * 128 + (((jrow >> 3) ^ (row & 7)) << 3) + (jrow & 7)] = f2bf(p[rr]);
    }
    if (c == 0) {
        #pragma unroll
        for (int rr = 0; rr < 4; ++rr)
            red[((g << 2) + rr) * 8 + w] = psv[rr];
    }
    __syncthreads(); // bar2: hT + alpha + red ready

    // ---- row inverse sums (broadcast reads) ----
    float inv[4];
    #pragma unroll
    for (int rr = 0; rr < 4; ++rr) {
        int row = (g << 2) + rr;
        float4 s0 = *reinterpret_cast<const float4*>(&red[row * 8]);
        float4 s1 = *reinterpret_cast<const float4*>(&red[row * 8 + 4]);
        float S = ((s0.x + s0.y) + (s0.z + s0.w)) + ((s1.x + s1.y) + (s1.z + s1.w));
        inv[rr] = 1.0f / S;
    }

    // ---- phase 3: out = (unnorm alpha @ h) * inv; wave w -> d-tile w ----
    floatx4 oa = (floatx4){0.f, 0.f, 0.f, 0.f};
    const int drow = jrow;
    #pragma unroll
    for (int s = 0; s < 4; ++s) {
        int ch = (s << 2) + g;
        short8 afr = *reinterpret_cast<const short8*>(&al[c * 128 + ((ch ^ (c & 7)) << 3)]);
        short8 bfr = *reinterpret_cast<const short8*>(
            &h_lds[drow * 128 + ((ch ^ (drow & 7)) << 3)]);
        oa = __builtin_amdgcn_mfma_f32_16x16x32_bf16(afr, bfr, oa, 0, 0, 0);
    }
    float* __restrict__ ob = out + ((size_t)b << 14);
    #pragma unroll
    for (int rr = 0; rr < 4; ++rr)
        ob[(size_t)(i0 + (g << 2) + rr) * 128 + drow] = oa[rr] * inv[rr];
}

extern "C" void kernel_launch(void* const* d_in, const int* in_sizes, int n_in,
                              void* d_out, int out_size, void* d_ws, size_t ws_size,
                              hipStream_t stream) {
    const float* h   = (const float*)d_in[0];
    const int*   adj = (const int*)d_in[1];
    const float* a0  = (const float*)d_in[2];
    const float* a1  = (const float*)d_in[3];
    const float* a2  = (const float*)d_in[4];
    const float* a3  = (const float*)d_in[5];
    float* out = (float*)d_out;
    (void)d_ws; (void)ws_size; (void)in_sizes; (void)n_in; (void)out_size;
    gat_fused<<<dim3(512), dim3(512), 0, stream>>>(h, adj, a0, a1, a2, a3, out);
}

// Round 7
// 13.180 us; speedup vs baseline: 2.0546x; 1.0298x over previous
//
#include <hip/hip_runtime.h>
#include <hip/hip_bf16.h>

typedef short short8 __attribute__((ext_vector_type(8)));
typedef float floatx4 __attribute__((ext_vector_type(4)));

#define NEG_INF -9.0e15f

// f32 -> bf16 RNE; adjacent pairs compile to v_cvt_pk_bf16_f32
__device__ __forceinline__ unsigned short fbf(float x) {
    __hip_bfloat16 b = __float2bfloat16(x);
    return __builtin_bit_cast(unsigned short, b);
}

__global__ __launch_bounds__(512, 4) void gat_fused(
    const float* __restrict__ h,
    const int*   __restrict__ adj,
    const float* __restrict__ a0, const float* __restrict__ a1,
    const float* __restrict__ a2, const float* __restrict__ a3,
    float* __restrict__ out)
{
    // 32 KB h-tile (becomes hT in place) + 16 KB union = 48 KB -> 2 blocks/CU
    __shared__ __align__(16) unsigned short h_lds[128 * 128]; // [j][d] swizzled, later [d][j]
    __shared__ __align__(16) unsigned char  u_lds[16384];     // G | red+alpha

    unsigned short* Gl  = reinterpret_cast<unsigned short*>(u_lds);        // [4][16][128] bf16
    float*          red = reinterpret_cast<float*>(u_lds);                 // [16][8] partial sums
    unsigned short* al  = reinterpret_cast<unsigned short*>(u_lds + 512);  // [16][128] bf16 (unnormalized)

    const int tid = threadIdx.x;
    const int B_  = blockIdx.x;
    // XCD-colocate the 8 i-strips of each b
    const int b   = ((B_ & 7) << 3) + (B_ >> 6);
    const int i0  = ((B_ >> 3) & 7) << 4;

    const int w    = tid >> 6;   // wave 0..7
    const int lane = tid & 63;
    const int c    = lane & 15;
    const int g    = lane >> 4;
    const int jrow = (w << 4) + c;

    const float* __restrict__ hb = h + ((size_t)b << 14);

    // ---- adj loads (issued early; 4 regs live) ----
    int adjv[4];
    #pragma unroll
    for (int rr = 0; rr < 4; ++rr)
        adjv[rr] = adj[((size_t)b << 14) + (size_t)(i0 + (g << 2) + rr) * 128 + jrow];

    // ---- G build first: Gl[k][i_loc][d] = bf16(h*a_k); source regs die here ----
    {
        const int gk = tid >> 7;          // k (wave-uniform)
        const int gr = (tid >> 3) & 15;   // i_loc
        const int gd = (tid & 7) << 4;    // d0
        const float* __restrict__ ap = (gk == 0) ? a0 : (gk == 1) ? a1 : (gk == 2) ? a2 : a3;
        float hv[16], av[16];
        #pragma unroll
        for (int q = 0; q < 4; ++q) {
            *reinterpret_cast<float4*>(&hv[q * 4]) =
                *reinterpret_cast<const float4*>(&hb[(i0 + gr) * 128 + gd + q * 4]);
            *reinterpret_cast<float4*>(&av[q * 4]) =
                *reinterpret_cast<const float4*>(&ap[gd + q * 4]);
        }
        short8 g0, g1;
        #pragma unroll
        for (int e = 0; e < 8; ++e) {
            g0[e] = (short)fbf(hv[e]     * av[e]);
            g1[e] = (short)fbf(hv[8 + e] * av[8 + e]);
        }
        const int cb   = gd >> 3;
        const int base = (gk << 11) + gr * 128;
        *reinterpret_cast<short8*>(&Gl[base + ((cb ^ (gr & 7)) << 3)])       = g0;
        *reinterpret_cast<short8*>(&Gl[base + (((cb + 1) ^ (gr & 7)) << 3)]) = g1;
    }

    // ---- stage h_lds: bf16, 16B-chunk XOR swizzle (proven layout) ----
    {
        const float4* __restrict__ src = reinterpret_cast<const float4*>(hb);
        #pragma unroll
        for (int it = 0; it < 8; ++it) {
            int id  = (it << 9) + tid;
            int row = id >> 5, c4 = id & 31;
            float4 v = src[id];
            short4 pk;
            pk.x = (short)fbf(v.x); pk.y = (short)fbf(v.y);
            pk.z = (short)fbf(v.z); pk.w = (short)fbf(v.w);
            *reinterpret_cast<short4*>(
                &h_lds[row * 128 + (((c4 >> 1) ^ (row & 7)) << 3) + ((c4 & 1) << 2)]) = pk;
        }
    }
    __syncthreads(); // bar0: h_lds + Gl ready

    // ---- phase 1: e_k tiles (wave w -> j-tile w) ----
    floatx4 acc[4];
    #pragma unroll
    for (int k = 0; k < 4; ++k) acc[k] = (floatx4){0.f, 0.f, 0.f, 0.f};
    #pragma unroll
    for (int s = 0; s < 4; ++s) {
        int ch = (s << 2) + g;
        short8 bfr = *reinterpret_cast<const short8*>(
            &h_lds[jrow * 128 + ((ch ^ (jrow & 7)) << 3)]);
        #pragma unroll
        for (int k = 0; k < 4; ++k) {
            short8 gfr = *reinterpret_cast<const short8*>(
                &Gl[(k << 11) + c * 128 + ((ch ^ (c & 7)) << 3)]);
            acc[k] = __builtin_amdgcn_mfma_f32_16x16x32_bf16(gfr, bfr, acc[k], 0, 0, 0);
        }
    }

    // ---- transpose gather (reads h_lds before bar1; packed immediately) ----
    const int jp = lane;           // j-pair 0..63 (wave covers all rows)
    const int dq = w;              // d-chunk-of-16
    const int r0 = 2 * jp, r1 = 2 * jp + 1;
    short8 t00 = *reinterpret_cast<const short8*>(&h_lds[r0 * 128 + (((2 * dq)     ^ (r0 & 7)) << 3)]);
    short8 t01 = *reinterpret_cast<const short8*>(&h_lds[r0 * 128 + (((2 * dq + 1) ^ (r0 & 7)) << 3)]);
    short8 t10 = *reinterpret_cast<const short8*>(&h_lds[r1 * 128 + (((2 * dq)     ^ (r1 & 7)) << 3)]);
    short8 t11 = *reinterpret_cast<const short8*>(&h_lds[r1 * 128 + (((2 * dq + 1) ^ (r1 & 7)) << 3)]);
    unsigned int tw[16];
    #pragma unroll
    for (int e = 0; e < 8; ++e) {
        tw[e]     = (unsigned int)(unsigned short)t00[e] | ((unsigned int)(unsigned short)t10[e] << 16);
        tw[8 + e] = (unsigned int)(unsigned short)t01[e] | ((unsigned int)(unsigned short)t11[e] << 16);
    }

    // ---- select + leaky-relu + mask + exp; no-max softmax (scores bounded) ----
    float p[4], psv[4];
    #pragma unroll
    for (int rr = 0; rr < 4; ++rr) {
        int cd = adjv[rr];
        float v = (cd == 1) ? acc[0][rr] : (cd == 2) ? acc[1][rr] :
                  (cd == 3) ? acc[2][rr] : acc[3][rr];
        v = (v > 0.f) ? v : 0.2f * v;
        float scv = (cd == 0) ? NEG_INF : v;
        float ev = __expf(scv);                 // masked -> 0
        float ss = ev;
        #pragma unroll
        for (int mk = 1; mk < 16; mk <<= 1) ss += __shfl_xor(ss, mk);
        p[rr] = ev; psv[rr] = ss;
    }
    __syncthreads(); // bar1: ALL h_lds + Gl reads complete

    // ---- in-place transpose write (h_lds -> hT), UNNORMALIZED alpha, red partials ----
    #pragma unroll
    for (int e = 0; e < 16; ++e) {
        int d    = (dq << 4) + e;
        int elem = d * 128 + (((jp >> 2) ^ (d & 7)) << 3) + ((jp & 3) << 1);
        *reinterpret_cast<unsigned int*>(&h_lds[elem]) = tw[e];
    }
    #pragma unroll
    for (int rr = 0; rr < 4; ++rr) {
        int row = (g << 2) + rr;
        al[row * 128 + (((jrow >> 3) ^ (row & 7)) << 3) + (jrow & 7)] = fbf(p[rr]);
    }
    if (c == 0) {
        #pragma unroll
        for (int rr = 0; rr < 4; ++rr)
            red[((g << 2) + rr) * 8 + w] = psv[rr];
    }
    __syncthreads(); // bar2: hT + alpha + red ready

    // ---- row inverse sums (broadcast reads) ----
    float inv[4];
    #pragma unroll
    for (int rr = 0; rr < 4; ++rr) {
        int row = (g << 2) + rr;
        float4 s0 = *reinterpret_cast<const float4*>(&red[row * 8]);
        float4 s1 = *reinterpret_cast<const float4*>(&red[row * 8 + 4]);
        float S = ((s0.x + s0.y) + (s0.z + s0.w)) + ((s1.x + s1.y) + (s1.z + s1.w));
        inv[rr] = 1.0f / S;
    }

    // ---- phase 3: out = (unnorm alpha @ h) * inv; wave w -> d-tile w ----
    floatx4 oa = (floatx4){0.f, 0.f, 0.f, 0.f};
    const int drow = jrow;
    #pragma unroll
    for (int s = 0; s < 4; ++s) {
        int ch = (s << 2) + g;
        short8 afr = *reinterpret_cast<const short8*>(&al[c * 128 + ((ch ^ (c & 7)) << 3)]);
        short8 bfr = *reinterpret_cast<const short8*>(
            &h_lds[drow * 128 + ((ch ^ (drow & 7)) << 3)]);
        oa = __builtin_amdgcn_mfma_f32_16x16x32_bf16(afr, bfr, oa, 0, 0, 0);
    }
    float* __restrict__ ob = out + ((size_t)b << 14);
    #pragma unroll
    for (int rr = 0; rr < 4; ++rr)
        ob[(size_t)(i0 + (g << 2) + rr) * 128 + drow] = oa[rr] * inv[rr];
}

extern "C" void kernel_launch(void* const* d_in, const int* in_sizes, int n_in,
                              void* d_out, int out_size, void* d_ws, size_t ws_size,
                              hipStream_t stream) {
    const float* h   = (const float*)d_in[0];
    const int*   adj = (const int*)d_in[1];
    const float* a0  = (const float*)d_in[2];
    const float* a1  = (const float*)d_in[3];
    const float* a2  = (const float*)d_in[4];
    const float* a3  = (const float*)d_in[5];
    float* out = (float*)d_out;
    (void)d_ws; (void)ws_size; (void)in_sizes; (void)n_in; (void)out_size;
    gat_fused<<<dim3(512), dim3(512), 0, stream>>>(h, adj, a0, a1, a2, a3, out);
}